// Round 5
// baseline (280.159 us; speedup 1.0000x reference)
//
#include <hip/hip_runtime.h>

#define S_LEN 2048
#define D_DIM 1024
#define NH    16
#define HD    64
#define BATCH 4
#define M_ROWS 8192

typedef __attribute__((ext_vector_type(8))) short bf16x8;   // 8 bf16 = 4 VGPR
typedef __attribute__((ext_vector_type(4))) float f32x4;
typedef __attribute__((ext_vector_type(8))) unsigned short u16x8;

__device__ __forceinline__ unsigned short f2bf(float f) {
    unsigned u = __builtin_bit_cast(unsigned, f);
    u = (u + 0x7fffu + ((u >> 16) & 1u)) >> 16;   // RNE
    return (unsigned short)u;
}
// round-half-up pack of two f32 -> packed bf16x2 (bias cancels: l from same P)
__device__ __forceinline__ unsigned pack2(float a, float b) {
    unsigned ua = __builtin_bit_cast(unsigned, a);
    unsigned ub = __builtin_bit_cast(unsigned, b);
    return ((ua + 0x8000u) >> 16) | ((ub + 0x8000u) & 0xffff0000u);
}

__device__ __forceinline__ void gload16(const void* g, void* l) {
    __builtin_amdgcn_global_load_lds((const __attribute__((address_space(1))) unsigned*)g,
                                     (__attribute__((address_space(3))) unsigned*)l,
                                     16, 0, 0);
}

// ---------------------------------------------------------------------------
// x fp32 -> bf16
// ---------------------------------------------------------------------------
__global__ __launch_bounds__(256) void castx_k(const float* __restrict__ x,
                                               unsigned short* __restrict__ o) {
    size_t i = (size_t)blockIdx.x * 256 + threadIdx.x;
    const float4* xf = (const float4*)x;
    float4 a = xf[2 * i], b = xf[2 * i + 1];
    u16x8 v;
    v[0] = f2bf(a.x); v[1] = f2bf(a.y); v[2] = f2bf(a.z); v[3] = f2bf(a.w);
    v[4] = f2bf(b.x); v[5] = f2bf(b.y); v[6] = f2bf(b.z); v[7] = f2bf(b.w);
    *(u16x8*)(o + i * 8) = v;
}

// ---------------------------------------------------------------------------
// W fp32 [K][N] -> bf16 transposed [N][K]; wq pre-scaled by 0.125*log2(e).
// ---------------------------------------------------------------------------
__global__ __launch_bounds__(256) void wprep_k(const float* __restrict__ w0, const float* __restrict__ w1,
                                               const float* __restrict__ w2, const float* __restrict__ w3,
                                               unsigned short* __restrict__ o0, unsigned short* __restrict__ o1,
                                               unsigned short* __restrict__ o2, unsigned short* __restrict__ o3) {
    __shared__ float sT[64][65];
    const float* w; unsigned short* o;
    switch (blockIdx.z) {
        case 0: w = w0; o = o0; break;
        case 1: w = w1; o = o1; break;
        case 2: w = w2; o = o2; break;
        default: w = w3; o = o3; break;
    }
    const float sc = (blockIdx.z == 0) ? 0.18033688011112042f : 1.0f;
    const int t = threadIdx.x;
    const int k0 = blockIdx.y * 64, n0 = blockIdx.x * 64;
    const int r = t >> 4, cq = t & 15;
#pragma unroll
    for (int it = 0; it < 4; ++it) {
        int k = r + it * 16;
        float4 v = *(const float4*)&w[(size_t)(k0 + k) * D_DIM + n0 + cq * 4];
        sT[k][cq * 4 + 0] = v.x; sT[k][cq * 4 + 1] = v.y;
        sT[k][cq * 4 + 2] = v.z; sT[k][cq * 4 + 3] = v.w;
    }
    __syncthreads();
    const int n = t >> 2, ch = t & 3;
    union { unsigned short s[8]; uint4 v; } p0, p1;
#pragma unroll
    for (int j = 0; j < 8; ++j) p0.s[j] = f2bf(sT[ch * 16 + j][n] * sc);
#pragma unroll
    for (int j = 0; j < 8; ++j) p1.s[j] = f2bf(sT[ch * 16 + 8 + j][n] * sc);
    *(uint4*)&o[(size_t)(n0 + n) * D_DIM + k0 + ch * 16]     = p0.v;
    *(uint4*)&o[(size_t)(n0 + n) * D_DIM + k0 + ch * 16 + 8] = p1.v;
}

// ---------------------------------------------------------------------------
// Shared double-buffered GEMM mainloop: acc = A(128 rows) x Bt(128 rows)^T
// over K=1024, BK=32. One barrier per K-iter; prefetch issued right after the
// barrier into the other buffer (drain distance = one full compute phase).
// sA/sB: 2 buffers x 128x32 bf16 (8KB each).
// ---------------------------------------------------------------------------
__device__ __forceinline__ void gemm_core(const unsigned short* __restrict__ A,
                                          const unsigned short* __restrict__ Bt,
                                          unsigned short* sA, unsigned short* sB,
                                          int m0, int n0, int t, f32x4 acc[4][4])
{
    const int lane = t & 63, w = t >> 6;
    const int mm = lane & 15, quad = lane >> 4;
    const int wm = w >> 1, wn = w & 1;

    auto stage = [&](int k0, int bufi) {
#pragma unroll
        for (int it = 0; it < 2; ++it) {
            int idx = t + it * 256;          // 0..511 = 128 rows x 4 chunks
            int m = idx >> 2, j = idx & 3;
            int g = (j - (m >> 1)) & 3;      // chunk-rotation swizzle
            gload16(A  + ((size_t)(m0 + m) * D_DIM + k0 + g * 8), (void*)&sA[bufi * 4096 + idx * 8]);
            gload16(Bt + ((size_t)(n0 + m) * D_DIM + k0 + g * 8), (void*)&sB[bufi * 4096 + idx * 8]);
        }
    };

    stage(0, 0);
    for (int kt = 0; kt < D_DIM / 32; ++kt) {
        const int bufo = (kt & 1) * 4096;
        __syncthreads();                     // drains prefetch issued last iter
        if (kt + 1 < D_DIM / 32) stage((kt + 1) * 32, 1 - (kt & 1));

        bf16x8 af[4], bfr[4];
#pragma unroll
        for (int mi = 0; mi < 4; ++mi) {
            int m = wm * 64 + mi * 16 + mm;
            int slot = (quad + (m >> 1)) & 3;
            af[mi] = *(const bf16x8*)&sA[bufo + m * 32 + slot * 8];
        }
#pragma unroll
        for (int ni = 0; ni < 4; ++ni) {
            int n = wn * 64 + ni * 16 + mm;
            int slot = (quad + (n >> 1)) & 3;
            bfr[ni] = *(const bf16x8*)&sB[bufo + n * 32 + slot * 8];
        }
#pragma unroll
        for (int mi = 0; mi < 4; ++mi)
#pragma unroll
            for (int ni = 0; ni < 4; ++ni)
                acc[mi][ni] = __builtin_amdgcn_mfma_f32_16x16x32_bf16(af[mi], bfr[ni], acc[mi][ni], 0, 0, 0);
    }
}

// ---------------------------------------------------------------------------
// Fused QKV GEMM. n covers [Wq|Wk|Wv] (N=3072). Q,K written bf16 row-major;
// V written directly transposed per head into vt[bh][hd][s] (acc regs hold 4
// consecutive s for fixed hd -> packed 8B store; transpose is free).
// ---------------------------------------------------------------------------
__global__ __launch_bounds__(256) void gemmqkv_k(const unsigned short* __restrict__ A,
                                                 const unsigned short* __restrict__ Bt,
                                                 unsigned short* __restrict__ qb,
                                                 unsigned short* __restrict__ kb,
                                                 unsigned short* __restrict__ vt)
{
    __shared__ unsigned short sA[2 * 128 * 32];
    __shared__ unsigned short sB[2 * 128 * 32];
    const int t = threadIdx.x;
    const int lane = t & 63, w = t >> 6;
    const int mm = lane & 15, quad = lane >> 4;
    const int wm = w >> 1, wn = w & 1;
    const int m0 = blockIdx.y * 128, n0 = blockIdx.x * 128;

    f32x4 acc[4][4];
#pragma unroll
    for (int i = 0; i < 4; ++i)
#pragma unroll
        for (int j = 0; j < 4; ++j) acc[i][j] = (f32x4){0.f, 0.f, 0.f, 0.f};

    gemm_core(A, Bt, sA, sB, m0, n0, t, acc);

    const int widx = n0 >> 10;
    if (widx == 2) {
        // V: write transposed per head
#pragma unroll
        for (int mi = 0; mi < 4; ++mi) {
            int rglob = m0 + wm * 64 + mi * 16 + quad * 4;
            int bb = rglob >> 11, ss = rglob & (S_LEN - 1);
#pragma unroll
            for (int ni = 0; ni < 4; ++ni) {
                int c = (n0 & 1023) + wn * 64 + ni * 16 + mm;
                int h = c >> 6, hd = c & 63;
                union { unsigned short s[4]; unsigned long long ll; } pk;
#pragma unroll
                for (int r = 0; r < 4; ++r) pk.s[r] = f2bf(acc[mi][ni][r]);
                *(unsigned long long*)&vt[((size_t)(bb * NH + h) * HD + hd) * S_LEN + ss] = pk.ll;
            }
        }
    } else {
        unsigned short* outp = widx ? kb : qb;
        const int nl0 = n0 & 1023;
#pragma unroll
        for (int mi = 0; mi < 4; ++mi)
#pragma unroll
            for (int ni = 0; ni < 4; ++ni)
#pragma unroll
                for (int r = 0; r < 4; ++r)
                    outp[(size_t)(m0 + wm * 64 + mi * 16 + quad * 4 + r) * D_DIM +
                         nl0 + wn * 64 + ni * 16 + mm] = f2bf(acc[mi][ni][r]);
    }
}

// ---------------------------------------------------------------------------
// Output GEMM: out_fp32 = ctx_bf16 * WoT^T
// ---------------------------------------------------------------------------
__global__ __launch_bounds__(256) void gemmo_k(const unsigned short* __restrict__ A,
                                               const unsigned short* __restrict__ Bt,
                                               float* __restrict__ C)
{
    __shared__ unsigned short sA[2 * 128 * 32];
    __shared__ unsigned short sB[2 * 128 * 32];
    const int t = threadIdx.x;
    const int lane = t & 63, w = t >> 6;
    const int mm = lane & 15, quad = lane >> 4;
    const int wm = w >> 1, wn = w & 1;
    const int m0 = blockIdx.y * 128, n0 = blockIdx.x * 128;

    f32x4 acc[4][4];
#pragma unroll
    for (int i = 0; i < 4; ++i)
#pragma unroll
        for (int j = 0; j < 4; ++j) acc[i][j] = (f32x4){0.f, 0.f, 0.f, 0.f};

    gemm_core(A, Bt, sA, sB, m0, n0, t, acc);

#pragma unroll
    for (int mi = 0; mi < 4; ++mi)
#pragma unroll
        for (int ni = 0; ni < 4; ++ni)
#pragma unroll
            for (int r = 0; r < 4; ++r)
                C[(size_t)(m0 + wm * 64 + mi * 16 + quad * 4 + r) * D_DIM +
                  n0 + wn * 64 + ni * 16 + mm] = acc[mi][ni][r];
}

// ---------------------------------------------------------------------------
// Fused causal flash attention, bf16 MFMA, fixed-max softmax.
// 512 threads (8 waves), 16 q-rows/wave, block covers strips {qt, 15-qt}
// (uniform 17 staged tiles). Tiles are 128 keys: staged once (double-
// buffered, prefetch-after-barrier), computed as two sequential 64-key
// halves -> half the barriers of round 4 per unit work.
// l computed via MFMA against all-ones B; sP rows are wave-private.
// ---------------------------------------------------------------------------
__global__ __launch_bounds__(512, 4) void attn_k(const unsigned short* __restrict__ Q,
                                                 const unsigned short* __restrict__ K,
                                                 const unsigned short* __restrict__ Vt,
                                                 unsigned short* __restrict__ ctx)
{
    __shared__ unsigned short sK [2][128 * 64];   // [buf][key][hd]  2x16KB
    __shared__ unsigned short sVT[2][64 * 128];   // [buf][hd][key]  2x16KB
    __shared__ unsigned short sP [128 * 64];      // [qrow][key]     16KB
    const int t = threadIdx.x;
    const int lane = t & 63, w = t >> 6;          // w = 0..7
    const int mm = lane & 15, quad = lane >> 4;
    const int pair = blockIdx.x, bh = blockIdx.y;
    const int b = bh >> 4, hh = bh & 15;
    const size_t rowbase = (size_t)b * S_LEN;
    const int coff = hh * HD;
    const unsigned short* Vh = Vt + (size_t)bh * HD * S_LEN;

    auto stage = [&](int kt, int bufi) {
#pragma unroll
        for (int it = 0; it < 2; ++it) {
            int idx = t + it * 512;               // 0..1023
            int key = idx >> 3, jk = idx & 7, gk = jk ^ (key & 7);
            gload16(K + (rowbase + kt * 128 + key) * D_DIM + coff + gk * 8,
                    (void*)&sK[bufi][idx * 8]);
            int hd = idx >> 4, jv = idx & 15, gv = jv ^ (hd & 15);
            gload16(Vh + (size_t)hd * S_LEN + kt * 128 + gv * 8,
                    (void*)&sVT[bufi][idx * 8]);
        }
    };

    u16x8 onesu;
#pragma unroll
    for (int j = 0; j < 8; ++j) onesu[j] = 0x3F80;   // bf16 1.0
    const bf16x8 ones = __builtin_bit_cast(bf16x8, onesu);

    for (int sidx = 0; sidx < 2; ++sidx) {
        const int qt = sidx ? (15 - pair) : pair;
        const int q0 = qt * 128;

        bf16x8 qf[2];
#pragma unroll
        for (int kk = 0; kk < 2; ++kk)
            qf[kk] = *(const bf16x8*)(Q + (rowbase + q0 + w * 16 + mm) * D_DIM
                                        + coff + kk * 32 + quad * 8);
        f32x4 o[4], lacc;
        lacc = (f32x4){0.f, 0.f, 0.f, 0.f};
#pragma unroll
        for (int hf = 0; hf < 4; ++hf) o[hf] = (f32x4){0.f, 0.f, 0.f, 0.f};

        const int nkt = qt + 1;                    // 128-key tiles
        const int qr = q0 + w * 16 + mm;           // this lane's q-row
        const int qrmax = q0 + w * 16 + 15;        // wave's max q-row
        const int m = w * 16 + mm;                 // sP row

        stage(0, 0);
        for (int kt = 0; kt < nkt; ++kt) {
            const int buf = kt & 1;
            __syncthreads();   // drains prefetch issued a full phase ago
            if (kt + 1 < nkt) stage(kt + 1, 1 - buf);

#pragma unroll
            for (int kh = 0; kh < 2; ++kh) {
                const int k0 = kt * 128 + kh * 64;
                if (k0 > qrmax) continue;          // wave-uniform skip

                // S^T = K Q^T
                f32x4 sacc[4];
#pragma unroll
                for (int kf = 0; kf < 4; ++kf) sacc[kf] = (f32x4){0.f, 0.f, 0.f, 0.f};
#pragma unroll
                for (int kk = 0; kk < 2; ++kk) {
                    bf16x8 ak[4];
#pragma unroll
                    for (int kf = 0; kf < 4; ++kf) {
                        int key = kh * 64 + kf * 16 + mm;
                        int slot = (kk * 4 + quad) ^ (key & 7);
                        ak[kf] = *(const bf16x8*)&sK[buf][key * 64 + slot * 8];
                    }
#pragma unroll
                    for (int kf = 0; kf < 4; ++kf)
                        sacc[kf] = __builtin_amdgcn_mfma_f32_16x16x32_bf16(ak[kf], qf[kk], sacc[kf], 0, 0, 0);
                }

                // p = exp2(s), causal mask -> 0, pack to wave-private sP rows
                const bool needmask = (k0 + 63) > (q0 + w * 16);
#pragma unroll
                for (int kf = 0; kf < 4; ++kf) {
                    float p[4];
#pragma unroll
                    for (int r = 0; r < 4; ++r) {
                        p[r] = __builtin_amdgcn_exp2f(sacc[kf][r]);
                        if (needmask && (k0 + kf * 16 + quad * 4 + r) > qr) p[r] = 0.f;
                    }
                    unsigned lo = pack2(p[0], p[1]), hi = pack2(p[2], p[3]);
                    int slot = (kf * 2 + (quad >> 1)) ^ (m & 7);
                    *(unsigned long long*)&sP[m * 64 + slot * 8 + (quad & 1) * 4] =
                        ((unsigned long long)hi << 32) | lo;
                }

                // O += P V ; l += P * ones
#pragma unroll
                for (int kk = 0; kk < 2; ++kk) {
                    bf16x8 pf, vf[4];
                    {
                        int slot = (kk * 4 + quad) ^ (m & 7);
                        pf = *(const bf16x8*)&sP[m * 64 + slot * 8];
                    }
#pragma unroll
                    for (int hf = 0; hf < 4; ++hf) {
                        int hd = hf * 16 + mm;
                        int c = kh * 8 + kk * 4 + quad;
                        int slot = c ^ (hd & 15);
                        vf[hf] = *(const bf16x8*)&sVT[buf][hd * 128 + slot * 8];
                    }
                    lacc = __builtin_amdgcn_mfma_f32_16x16x32_bf16(pf, ones, lacc, 0, 0, 0);
#pragma unroll
                    for (int hf = 0; hf < 4; ++hf)
                        o[hf] = __builtin_amdgcn_mfma_f32_16x16x32_bf16(pf, vf[hf], o[hf], 0, 0, 0);
                }
            }
        }
        __syncthreads();   // all reads done before next strip restages buf0

        // normalize (l already in C-layout) and store ctx
#pragma unroll
        for (int r = 0; r < 4; ++r) {
            float inv = 1.f / lacc[r];
            int row = q0 + w * 16 + quad * 4 + r;
#pragma unroll
            for (int hf = 0; hf < 4; ++hf)
                ctx[(rowbase + row) * D_DIM + coff + hf * 16 + mm] = f2bf(o[hf][r] * inv);
        }
    }
}

extern "C" void kernel_launch(void* const* d_in, const int* in_sizes, int n_in,
                              void* d_out, int out_size, void* d_ws, size_t ws_size,
                              hipStream_t stream)
{
    const float* x  = (const float*)d_in[0];
    const float* wq = (const float*)d_in[1];
    const float* wk = (const float*)d_in[2];
    const float* wv = (const float*)d_in[3];
    const float* wo = (const float*)d_in[4];

    const size_t XE = (size_t)M_ROWS * D_DIM;   // 8M elems
    const size_t WE = (size_t)D_DIM * D_DIM;    // 1M elems
    unsigned short* ws  = (unsigned short*)d_ws;
    unsigned short* xbf = ws;
    unsigned short* wt0 = xbf + XE;
    unsigned short* wt1 = wt0 + WE;
    unsigned short* wt2 = wt1 + WE;
    unsigned short* wt3 = wt2 + WE;
    unsigned short* qb  = wt3 + WE;
    unsigned short* kb  = qb + XE;
    unsigned short* vt  = kb + XE;      // V stored transposed per head
    unsigned short* cb  = vt + XE;      // ~80 MB total

    castx_k<<<dim3(M_ROWS * D_DIM / (256 * 8)), 256, 0, stream>>>(x, xbf);
    wprep_k<<<dim3(16, 16, 4), 256, 0, stream>>>(wq, wk, wv, wo, wt0, wt1, wt2, wt3);

    gemmqkv_k<<<dim3(3 * D_DIM / 128, M_ROWS / 128), 256, 0, stream>>>(xbf, wt0, qb, kb, vt);

    attn_k<<<dim3(8, BATCH * NH), 512, 0, stream>>>(qb, kb, vt, cb);

    gemmo_k<<<dim3(D_DIM / 128, M_ROWS / 128), 256, 0, stream>>>(cb, wt3, (float*)d_out);
}

// Round 6
// 261.710 us; speedup vs baseline: 1.0705x; 1.0705x over previous
//
#include <hip/hip_runtime.h>

#define S_LEN 2048
#define D_DIM 1024
#define NH    16
#define HD    64
#define BATCH 4
#define M_ROWS 8192

typedef __attribute__((ext_vector_type(8))) short bf16x8;   // 8 bf16 = 4 VGPR
typedef __attribute__((ext_vector_type(4))) float f32x4;
typedef __attribute__((ext_vector_type(8))) unsigned short u16x8;

__device__ __forceinline__ unsigned short f2bf(float f) {
    unsigned u = __builtin_bit_cast(unsigned, f);
    u = (u + 0x7fffu + ((u >> 16) & 1u)) >> 16;   // RNE
    return (unsigned short)u;
}
// round-half-up pack of two f32 -> packed bf16x2 (bias cancels: l from same P)
__device__ __forceinline__ unsigned pack2(float a, float b) {
    unsigned ua = __builtin_bit_cast(unsigned, a);
    unsigned ub = __builtin_bit_cast(unsigned, b);
    return ((ua + 0x8000u) >> 16) | ((ub + 0x8000u) & 0xffff0000u);
}

__device__ __forceinline__ void gload16(const void* g, void* l) {
    __builtin_amdgcn_global_load_lds((const __attribute__((address_space(1))) unsigned*)g,
                                     (__attribute__((address_space(3))) unsigned*)l,
                                     16, 0, 0);
}

// ---------------------------------------------------------------------------
// x fp32 -> bf16
// ---------------------------------------------------------------------------
__global__ __launch_bounds__(256) void castx_k(const float* __restrict__ x,
                                               unsigned short* __restrict__ o) {
    size_t i = (size_t)blockIdx.x * 256 + threadIdx.x;
    const float4* xf = (const float4*)x;
    float4 a = xf[2 * i], b = xf[2 * i + 1];
    u16x8 v;
    v[0] = f2bf(a.x); v[1] = f2bf(a.y); v[2] = f2bf(a.z); v[3] = f2bf(a.w);
    v[4] = f2bf(b.x); v[5] = f2bf(b.y); v[6] = f2bf(b.z); v[7] = f2bf(b.w);
    *(u16x8*)(o + i * 8) = v;
}

// ---------------------------------------------------------------------------
// W fp32 [K][N] -> bf16 transposed [N][K]; wq pre-scaled by 0.125*log2(e).
// ---------------------------------------------------------------------------
__global__ __launch_bounds__(256) void wprep_k(const float* __restrict__ w0, const float* __restrict__ w1,
                                               const float* __restrict__ w2, const float* __restrict__ w3,
                                               unsigned short* __restrict__ o0, unsigned short* __restrict__ o1,
                                               unsigned short* __restrict__ o2, unsigned short* __restrict__ o3) {
    __shared__ float sT[64][65];
    const float* w; unsigned short* o;
    switch (blockIdx.z) {
        case 0: w = w0; o = o0; break;
        case 1: w = w1; o = o1; break;
        case 2: w = w2; o = o2; break;
        default: w = w3; o = o3; break;
    }
    const float sc = (blockIdx.z == 0) ? 0.18033688011112042f : 1.0f;
    const int t = threadIdx.x;
    const int k0 = blockIdx.y * 64, n0 = blockIdx.x * 64;
    const int r = t >> 4, cq = t & 15;
#pragma unroll
    for (int it = 0; it < 4; ++it) {
        int k = r + it * 16;
        float4 v = *(const float4*)&w[(size_t)(k0 + k) * D_DIM + n0 + cq * 4];
        sT[k][cq * 4 + 0] = v.x; sT[k][cq * 4 + 1] = v.y;
        sT[k][cq * 4 + 2] = v.z; sT[k][cq * 4 + 3] = v.w;
    }
    __syncthreads();
    const int n = t >> 2, ch = t & 3;
    union { unsigned short s[8]; uint4 v; } p0, p1;
#pragma unroll
    for (int j = 0; j < 8; ++j) p0.s[j] = f2bf(sT[ch * 16 + j][n] * sc);
#pragma unroll
    for (int j = 0; j < 8; ++j) p1.s[j] = f2bf(sT[ch * 16 + 8 + j][n] * sc);
    *(uint4*)&o[(size_t)(n0 + n) * D_DIM + k0 + ch * 16]     = p0.v;
    *(uint4*)&o[(size_t)(n0 + n) * D_DIM + k0 + ch * 16 + 8] = p1.v;
}

// ---------------------------------------------------------------------------
// Single-buffer m97-style GEMM mainloop (measured faster than dbuf variant:
// short BK=32 compute phase can't hide load latency; cross-block overlap at
// higher residency does the hiding instead). 2 barriers per K-iter.
// ---------------------------------------------------------------------------
__device__ __forceinline__ void gemm_core(const unsigned short* __restrict__ A,
                                          const unsigned short* __restrict__ Bt,
                                          unsigned short* sA, unsigned short* sB,
                                          int m0, int n0, int t, f32x4 acc[4][4])
{
    const int lane = t & 63, w = t >> 6;
    const int mm = lane & 15, quad = lane >> 4;
    const int wm = w >> 1, wn = w & 1;

    for (int k0 = 0; k0 < D_DIM; k0 += 32) {
        __syncthreads();
#pragma unroll
        for (int it = 0; it < 2; ++it) {
            int idx = t + it * 256;          // 0..511 = 128 rows x 4 chunks
            int m = idx >> 2, j = idx & 3;
            int g = (j - (m >> 1)) & 3;      // chunk-rotation swizzle
            gload16(A  + ((size_t)(m0 + m) * D_DIM + k0 + g * 8), (void*)&sA[idx * 8]);
            gload16(Bt + ((size_t)(n0 + m) * D_DIM + k0 + g * 8), (void*)&sB[idx * 8]);
        }
        __syncthreads();

        bf16x8 af[4], bfr[4];
#pragma unroll
        for (int mi = 0; mi < 4; ++mi) {
            int m = wm * 64 + mi * 16 + mm;
            int slot = (quad + (m >> 1)) & 3;
            af[mi] = *(const bf16x8*)&sA[m * 32 + slot * 8];
        }
#pragma unroll
        for (int ni = 0; ni < 4; ++ni) {
            int n = wn * 64 + ni * 16 + mm;
            int slot = (quad + (n >> 1)) & 3;
            bfr[ni] = *(const bf16x8*)&sB[n * 32 + slot * 8];
        }
#pragma unroll
        for (int mi = 0; mi < 4; ++mi)
#pragma unroll
            for (int ni = 0; ni < 4; ++ni)
                acc[mi][ni] = __builtin_amdgcn_mfma_f32_16x16x32_bf16(af[mi], bfr[ni], acc[mi][ni], 0, 0, 0);
    }
}

// ---------------------------------------------------------------------------
// Fused QKV GEMM. n covers [Wq|Wk|Wv] (N=3072). Q,K written bf16 row-major;
// V written directly transposed per head into vt[bh][hd][s] (acc regs hold 4
// consecutive s for fixed hd -> packed 8B store; transpose is free).
// ---------------------------------------------------------------------------
__global__ __launch_bounds__(256) void gemmqkv_k(const unsigned short* __restrict__ A,
                                                 const unsigned short* __restrict__ Bt,
                                                 unsigned short* __restrict__ qb,
                                                 unsigned short* __restrict__ kb,
                                                 unsigned short* __restrict__ vt)
{
    __shared__ unsigned short sA[128 * 32];
    __shared__ unsigned short sB[128 * 32];
    const int t = threadIdx.x;
    const int lane = t & 63, w = t >> 6;
    const int mm = lane & 15, quad = lane >> 4;
    const int wm = w >> 1, wn = w & 1;
    const int m0 = blockIdx.y * 128, n0 = blockIdx.x * 128;

    f32x4 acc[4][4];
#pragma unroll
    for (int i = 0; i < 4; ++i)
#pragma unroll
        for (int j = 0; j < 4; ++j) acc[i][j] = (f32x4){0.f, 0.f, 0.f, 0.f};

    gemm_core(A, Bt, sA, sB, m0, n0, t, acc);

    const int widx = n0 >> 10;
    if (widx == 2) {
        // V: write transposed per head
#pragma unroll
        for (int mi = 0; mi < 4; ++mi) {
            int rglob = m0 + wm * 64 + mi * 16 + quad * 4;
            int bb = rglob >> 11, ss = rglob & (S_LEN - 1);
#pragma unroll
            for (int ni = 0; ni < 4; ++ni) {
                int c = (n0 & 1023) + wn * 64 + ni * 16 + mm;
                int h = c >> 6, hd = c & 63;
                union { unsigned short s[4]; unsigned long long ll; } pk;
#pragma unroll
                for (int r = 0; r < 4; ++r) pk.s[r] = f2bf(acc[mi][ni][r]);
                *(unsigned long long*)&vt[((size_t)(bb * NH + h) * HD + hd) * S_LEN + ss] = pk.ll;
            }
        }
    } else {
        unsigned short* outp = widx ? kb : qb;
        const int nl0 = n0 & 1023;
#pragma unroll
        for (int mi = 0; mi < 4; ++mi)
#pragma unroll
            for (int ni = 0; ni < 4; ++ni)
#pragma unroll
                for (int r = 0; r < 4; ++r)
                    outp[(size_t)(m0 + wm * 64 + mi * 16 + quad * 4 + r) * D_DIM +
                         nl0 + wn * 64 + ni * 16 + mm] = f2bf(acc[mi][ni][r]);
    }
}

// ---------------------------------------------------------------------------
// Output GEMM: out_fp32 = ctx_bf16 * WoT^T
// ---------------------------------------------------------------------------
__global__ __launch_bounds__(256) void gemmo_k(const unsigned short* __restrict__ A,
                                               const unsigned short* __restrict__ Bt,
                                               float* __restrict__ C)
{
    __shared__ unsigned short sA[128 * 32];
    __shared__ unsigned short sB[128 * 32];
    const int t = threadIdx.x;
    const int lane = t & 63, w = t >> 6;
    const int mm = lane & 15, quad = lane >> 4;
    const int wm = w >> 1, wn = w & 1;
    const int m0 = blockIdx.y * 128, n0 = blockIdx.x * 128;

    f32x4 acc[4][4];
#pragma unroll
    for (int i = 0; i < 4; ++i)
#pragma unroll
        for (int j = 0; j < 4; ++j) acc[i][j] = (f32x4){0.f, 0.f, 0.f, 0.f};

    gemm_core(A, Bt, sA, sB, m0, n0, t, acc);

#pragma unroll
    for (int mi = 0; mi < 4; ++mi)
#pragma unroll
        for (int ni = 0; ni < 4; ++ni)
#pragma unroll
            for (int r = 0; r < 4; ++r)
                C[(size_t)(m0 + wm * 64 + mi * 16 + quad * 4 + r) * D_DIM +
                  n0 + wn * 64 + ni * 16 + mm] = acc[mi][ni][r];
}

// ---------------------------------------------------------------------------
// Fused causal flash attention (round-4 verified config: 74.5 us).
// 512 threads (8 waves), 16 q-rows/wave, block covers strips {qt, 15-qt}
// (uniform 34 k-tiles of 64 keys). K/V^T double-buffered, prefetch issued
// right after the per-tile barrier (long compute phase hides the drain).
// l computed via MFMA against all-ones B; sP rows are wave-private.
// ---------------------------------------------------------------------------
__global__ __launch_bounds__(512, 4) void attn_k(const unsigned short* __restrict__ Q,
                                                 const unsigned short* __restrict__ K,
                                                 const unsigned short* __restrict__ Vt,
                                                 unsigned short* __restrict__ ctx)
{
    __shared__ unsigned short sK [2][64 * 64];   // [buf][key][hd]   2x8KB
    __shared__ unsigned short sVT[2][64 * 64];   // [buf][hd][key]   2x8KB
    __shared__ unsigned short sP [128 * 64];     // [qrow][key]      16KB
    const int t = threadIdx.x;
    const int lane = t & 63, w = t >> 6;          // w = 0..7
    const int mm = lane & 15, quad = lane >> 4;
    const int pair = blockIdx.x, bh = blockIdx.y;
    const int b = bh >> 4, hh = bh & 15;
    const size_t rowbase = (size_t)b * S_LEN;
    const int coff = hh * HD;
    const unsigned short* Vh = Vt + (size_t)bh * HD * S_LEN;

    // staging geometry: 512 lanes cover one 64x128B tile per buffer
    const int sc_ = t >> 3, sj = t & 7;
    const int sgk = sj ^ (sc_ & 7);               // K rows (row=key, 8 chunks)

    u16x8 onesu;
#pragma unroll
    for (int j = 0; j < 8; ++j) onesu[j] = 0x3F80;   // bf16 1.0
    const bf16x8 ones = __builtin_bit_cast(bf16x8, onesu);

    for (int sidx = 0; sidx < 2; ++sidx) {
        const int qt = sidx ? (15 - pair) : pair;
        const int q0 = qt * 128;

        bf16x8 qf[2];
#pragma unroll
        for (int kk = 0; kk < 2; ++kk)
            qf[kk] = *(const bf16x8*)(Q + (rowbase + q0 + w * 16 + mm) * D_DIM
                                        + coff + kk * 32 + quad * 8);
        f32x4 o[4], lacc;
        lacc = (f32x4){0.f, 0.f, 0.f, 0.f};
#pragma unroll
        for (int hf = 0; hf < 4; ++hf) o[hf] = (f32x4){0.f, 0.f, 0.f, 0.f};

        const int nkt = 2 * qt + 2;
        const int qr = q0 + w * 16 + mm;          // this lane's q-row
        const int qrmax = q0 + w * 16 + 15;       // wave's max q-row
        const int m = w * 16 + mm;                // sP row

        // prologue: stage tile 0 into buf 0 (V^T staged by row=hd, 8 chunks)
        gload16(K  + (rowbase + sc_) * D_DIM + coff + sgk * 8, (void*)&sK[0][t * 8]);
        gload16(Vh + (size_t)sc_ * S_LEN + sgk * 8,            (void*)&sVT[0][t * 8]);

        for (int kt = 0; kt < nkt; ++kt) {
            const int buf = kt & 1;
            __syncthreads();   // buf's loads drained (issued a full phase ago)
            if (kt + 1 < nkt) {
                const int k1 = (kt + 1) * 64;
                gload16(K  + (rowbase + k1 + sc_) * D_DIM + coff + sgk * 8,
                        (void*)&sK[1 - buf][t * 8]);
                gload16(Vh + (size_t)sc_ * S_LEN + k1 + sgk * 8,
                        (void*)&sVT[1 - buf][t * 8]);
            }
            const int k0 = kt * 64;
            if (k0 > qrmax) continue;   // fully masked for this wave

            // S^T = K Q^T : A = K rows, B = Q rows
            f32x4 sacc[4];
#pragma unroll
            for (int kf = 0; kf < 4; ++kf) sacc[kf] = (f32x4){0.f, 0.f, 0.f, 0.f};
#pragma unroll
            for (int kk = 0; kk < 2; ++kk) {
                bf16x8 ak[4];
#pragma unroll
                for (int kf = 0; kf < 4; ++kf) {
                    int key = kf * 16 + mm;
                    int slot = (kk * 4 + quad) ^ (key & 7);
                    ak[kf] = *(const bf16x8*)&sK[buf][key * 64 + slot * 8];
                }
#pragma unroll
                for (int kf = 0; kf < 4; ++kf)
                    sacc[kf] = __builtin_amdgcn_mfma_f32_16x16x32_bf16(ak[kf], qf[kk], sacc[kf], 0, 0, 0);
            }

            // p = exp2(s), causal mask -> 0, pack to wave-private sP rows
            const bool needmask = (k0 + 63) > (q0 + w * 16);
#pragma unroll
            for (int kf = 0; kf < 4; ++kf) {
                float p[4];
#pragma unroll
                for (int r = 0; r < 4; ++r) {
                    p[r] = __builtin_amdgcn_exp2f(sacc[kf][r]);
                    if (needmask && (k0 + kf * 16 + quad * 4 + r) > qr) p[r] = 0.f;
                }
                unsigned lo = pack2(p[0], p[1]), hi = pack2(p[2], p[3]);
                int slot = (kf * 2 + (quad >> 1)) ^ (m & 7);
                *(unsigned long long*)&sP[m * 64 + slot * 8 + (quad & 1) * 4] =
                    ((unsigned long long)hi << 32) | lo;
            }

            // O += P V ; l += P * ones
#pragma unroll
            for (int kk = 0; kk < 2; ++kk) {
                bf16x8 pf, vf[4];
                {
                    int slot = (kk * 4 + quad) ^ (m & 7);
                    pf = *(const bf16x8*)&sP[m * 64 + slot * 8];
                }
#pragma unroll
                for (int hf = 0; hf < 4; ++hf) {
                    int hd = hf * 16 + mm;
                    int slot = (kk * 4 + quad) ^ (hd & 7);
                    vf[hf] = *(const bf16x8*)&sVT[buf][hd * 64 + slot * 8];
                }
                lacc = __builtin_amdgcn_mfma_f32_16x16x32_bf16(pf, ones, lacc, 0, 0, 0);
#pragma unroll
                for (int hf = 0; hf < 4; ++hf)
                    o[hf] = __builtin_amdgcn_mfma_f32_16x16x32_bf16(pf, vf[hf], o[hf], 0, 0, 0);
            }
        }
        __syncthreads();   // all compute done before next strip's prologue restages buf0

        // normalize (l already in C-layout) and store ctx
#pragma unroll
        for (int r = 0; r < 4; ++r) {
            float inv = 1.f / lacc[r];
            int row = q0 + w * 16 + quad * 4 + r;
#pragma unroll
            for (int hf = 0; hf < 4; ++hf)
                ctx[(rowbase + row) * D_DIM + coff + hf * 16 + mm] = f2bf(o[hf][r] * inv);
        }
    }
}

extern "C" void kernel_launch(void* const* d_in, const int* in_sizes, int n_in,
                              void* d_out, int out_size, void* d_ws, size_t ws_size,
                              hipStream_t stream)
{
    const float* x  = (const float*)d_in[0];
    const float* wq = (const float*)d_in[1];
    const float* wk = (const float*)d_in[2];
    const float* wv = (const float*)d_in[3];
    const float* wo = (const float*)d_in[4];

    const size_t XE = (size_t)M_ROWS * D_DIM;   // 8M elems
    const size_t WE = (size_t)D_DIM * D_DIM;    // 1M elems
    unsigned short* ws  = (unsigned short*)d_ws;
    unsigned short* xbf = ws;
    unsigned short* wt0 = xbf + XE;
    unsigned short* wt1 = wt0 + WE;
    unsigned short* wt2 = wt1 + WE;
    unsigned short* wt3 = wt2 + WE;
    unsigned short* qb  = wt3 + WE;
    unsigned short* kb  = qb + XE;
    unsigned short* vt  = kb + XE;      // V stored transposed per head
    unsigned short* cb  = vt + XE;      // ~80 MB total

    castx_k<<<dim3(M_ROWS * D_DIM / (256 * 8)), 256, 0, stream>>>(x, xbf);
    wprep_k<<<dim3(16, 16, 4), 256, 0, stream>>>(wq, wk, wv, wo, wt0, wt1, wt2, wt3);

    gemmqkv_k<<<dim3(3 * D_DIM / 128, M_ROWS / 128), 256, 0, stream>>>(xbf, wt0, qb, kb, vt);

    attn_k<<<dim3(8, BATCH * NH), 512, 0, stream>>>(qb, kb, vt, cb);

    gemmo_k<<<dim3(D_DIM / 128, M_ROWS / 128), 256, 0, stream>>>(cb, wt3, (float*)d_out);
}

// Round 7
// 251.192 us; speedup vs baseline: 1.1153x; 1.0419x over previous
//
#include <hip/hip_runtime.h>

#define S_LEN 2048
#define D_DIM 1024
#define NH    16
#define HD    64
#define BATCH 4
#define M_ROWS 8192

typedef __attribute__((ext_vector_type(8))) short bf16x8;   // 8 bf16 = 4 VGPR
typedef __attribute__((ext_vector_type(4))) float f32x4;
typedef __attribute__((ext_vector_type(8))) unsigned short u16x8;

__device__ __forceinline__ unsigned short f2bf(float f) {
    unsigned u = __builtin_bit_cast(unsigned, f);
    u = (u + 0x7fffu + ((u >> 16) & 1u)) >> 16;   // RNE
    return (unsigned short)u;
}
// round-half-up pack of two f32 -> packed bf16x2 (bias cancels: l from same P)
__device__ __forceinline__ unsigned pack2(float a, float b) {
    unsigned ua = __builtin_bit_cast(unsigned, a);
    unsigned ub = __builtin_bit_cast(unsigned, b);
    return ((ua + 0x8000u) >> 16) | ((ub + 0x8000u) & 0xffff0000u);
}

__device__ __forceinline__ void gload16(const void* g, void* l) {
    __builtin_amdgcn_global_load_lds((const __attribute__((address_space(1))) unsigned*)g,
                                     (__attribute__((address_space(3))) unsigned*)l,
                                     16, 0, 0);
}

// ---------------------------------------------------------------------------
// Merged prep: blocks [0,4096) cast x fp32->bf16; blocks [4096,5120) build
// W^T bf16 (wq pre-scaled by 0.125*log2(e)). One launch instead of two
// (saves ~10us inter-kernel gap).
// ---------------------------------------------------------------------------
__global__ __launch_bounds__(256) void prep_k(const float* __restrict__ x,
                                              const float* __restrict__ w0, const float* __restrict__ w1,
                                              const float* __restrict__ w2, const float* __restrict__ w3,
                                              unsigned short* __restrict__ xbf,
                                              unsigned short* __restrict__ o0, unsigned short* __restrict__ o1,
                                              unsigned short* __restrict__ o2, unsigned short* __restrict__ o3) {
    __shared__ float sT[64][65];
    const int t = threadIdx.x;
    if (blockIdx.x < 4096) {
        size_t i = (size_t)blockIdx.x * 256 + t;
        const float4* xf = (const float4*)x;
        float4 a = xf[2 * i], b = xf[2 * i + 1];
        u16x8 v;
        v[0] = f2bf(a.x); v[1] = f2bf(a.y); v[2] = f2bf(a.z); v[3] = f2bf(a.w);
        v[4] = f2bf(b.x); v[5] = f2bf(b.y); v[6] = f2bf(b.z); v[7] = f2bf(b.w);
        *(u16x8*)(xbf + i * 8) = v;
        return;
    }
    const int wb = blockIdx.x - 4096;          // 0..1023
    const int z = wb >> 8;                     // weight index
    const float* w; unsigned short* o;
    switch (z) {
        case 0: w = w0; o = o0; break;
        case 1: w = w1; o = o1; break;
        case 2: w = w2; o = o2; break;
        default: w = w3; o = o3; break;
    }
    const float sc = (z == 0) ? 0.18033688011112042f : 1.0f;
    const int n0 = (wb & 15) * 64, k0 = ((wb >> 4) & 15) * 64;
    const int r = t >> 4, cq = t & 15;
#pragma unroll
    for (int it = 0; it < 4; ++it) {
        int k = r + it * 16;
        float4 v = *(const float4*)&w[(size_t)(k0 + k) * D_DIM + n0 + cq * 4];
        sT[k][cq * 4 + 0] = v.x; sT[k][cq * 4 + 1] = v.y;
        sT[k][cq * 4 + 2] = v.z; sT[k][cq * 4 + 3] = v.w;
    }
    __syncthreads();
    const int n = t >> 2, ch = t & 3;
    union { unsigned short s[8]; uint4 v; } p0, p1;
#pragma unroll
    for (int j = 0; j < 8; ++j) p0.s[j] = f2bf(sT[ch * 16 + j][n] * sc);
#pragma unroll
    for (int j = 0; j < 8; ++j) p1.s[j] = f2bf(sT[ch * 16 + 8 + j][n] * sc);
    *(uint4*)&o[(size_t)(n0 + n) * D_DIM + k0 + ch * 16]     = p0.v;
    *(uint4*)&o[(size_t)(n0 + n) * D_DIM + k0 + ch * 16 + 8] = p1.v;
}

// ---------------------------------------------------------------------------
// Single-buffer GEMM mainloop, BK=64: half the barriers of BK=32 per unit K,
// 32 MFMA/wave per barrier pair. XOR chunk swizzle (slot = j ^ (row&7)) ->
// <=2-way LDS access everywhere (free). LDS 2x16KB.
// ---------------------------------------------------------------------------
__device__ __forceinline__ void gemm_core(const unsigned short* __restrict__ A,
                                          const unsigned short* __restrict__ Bt,
                                          unsigned short* sA, unsigned short* sB,
                                          int m0, int n0, int t, f32x4 acc[4][4])
{
    const int lane = t & 63, w = t >> 6;
    const int mm = lane & 15, quad = lane >> 4;
    const int wm = w >> 1, wn = w & 1;

    for (int k0 = 0; k0 < D_DIM; k0 += 64) {
        __syncthreads();
#pragma unroll
        for (int it = 0; it < 4; ++it) {
            int idx = t + it * 256;          // 0..1023 = 128 rows x 8 chunks
            int m = idx >> 3, j = idx & 7;
            int g = j ^ (m & 7);             // XOR chunk swizzle
            gload16(A  + ((size_t)(m0 + m) * D_DIM + k0 + g * 8), (void*)&sA[idx * 8]);
            gload16(Bt + ((size_t)(n0 + m) * D_DIM + k0 + g * 8), (void*)&sB[idx * 8]);
        }
        __syncthreads();

#pragma unroll
        for (int kk = 0; kk < 2; ++kk) {
            bf16x8 af[4], bfr[4];
#pragma unroll
            for (int mi = 0; mi < 4; ++mi) {
                int m = wm * 64 + mi * 16 + mm;
                int slot = (kk * 4 + quad) ^ (m & 7);
                af[mi] = *(const bf16x8*)&sA[m * 64 + slot * 8];
            }
#pragma unroll
            for (int ni = 0; ni < 4; ++ni) {
                int n = wn * 64 + ni * 16 + mm;
                int slot = (kk * 4 + quad) ^ (n & 7);
                bfr[ni] = *(const bf16x8*)&sB[n * 64 + slot * 8];
            }
#pragma unroll
            for (int mi = 0; mi < 4; ++mi)
#pragma unroll
                for (int ni = 0; ni < 4; ++ni)
                    acc[mi][ni] = __builtin_amdgcn_mfma_f32_16x16x32_bf16(af[mi], bfr[ni], acc[mi][ni], 0, 0, 0);
        }
    }
}

// ---------------------------------------------------------------------------
// Fused QKV GEMM. n covers [Wq|Wk|Wv] (N=3072). Q,K written bf16 row-major;
// V written directly transposed per head into vt[bh][hd][s] (acc regs hold 4
// consecutive s for fixed hd -> packed 8B store; transpose is free).
// ---------------------------------------------------------------------------
__global__ __launch_bounds__(256) void gemmqkv_k(const unsigned short* __restrict__ A,
                                                 const unsigned short* __restrict__ Bt,
                                                 unsigned short* __restrict__ qb,
                                                 unsigned short* __restrict__ kb,
                                                 unsigned short* __restrict__ vt)
{
    __shared__ unsigned short sA[128 * 64];
    __shared__ unsigned short sB[128 * 64];
    const int t = threadIdx.x;
    const int lane = t & 63, w = t >> 6;
    const int mm = lane & 15, quad = lane >> 4;
    const int wm = w >> 1, wn = w & 1;
    const int m0 = blockIdx.y * 128, n0 = blockIdx.x * 128;

    f32x4 acc[4][4];
#pragma unroll
    for (int i = 0; i < 4; ++i)
#pragma unroll
        for (int j = 0; j < 4; ++j) acc[i][j] = (f32x4){0.f, 0.f, 0.f, 0.f};

    gemm_core(A, Bt, sA, sB, m0, n0, t, acc);

    const int widx = n0 >> 10;
    if (widx == 2) {
        // V: write transposed per head
#pragma unroll
        for (int mi = 0; mi < 4; ++mi) {
            int rglob = m0 + wm * 64 + mi * 16 + quad * 4;
            int bb = rglob >> 11, ss = rglob & (S_LEN - 1);
#pragma unroll
            for (int ni = 0; ni < 4; ++ni) {
                int c = (n0 & 1023) + wn * 64 + ni * 16 + mm;
                int h = c >> 6, hd = c & 63;
                union { unsigned short s[4]; unsigned long long ll; } pk;
#pragma unroll
                for (int r = 0; r < 4; ++r) pk.s[r] = f2bf(acc[mi][ni][r]);
                *(unsigned long long*)&vt[((size_t)(bb * NH + h) * HD + hd) * S_LEN + ss] = pk.ll;
            }
        }
    } else {
        unsigned short* outp = widx ? kb : qb;
        const int nl0 = n0 & 1023;
#pragma unroll
        for (int mi = 0; mi < 4; ++mi)
#pragma unroll
            for (int ni = 0; ni < 4; ++ni)
#pragma unroll
                for (int r = 0; r < 4; ++r)
                    outp[(size_t)(m0 + wm * 64 + mi * 16 + quad * 4 + r) * D_DIM +
                         nl0 + wn * 64 + ni * 16 + mm] = f2bf(acc[mi][ni][r]);
    }
}

// ---------------------------------------------------------------------------
// Output GEMM: out_fp32 = ctx_bf16 * WoT^T
// ---------------------------------------------------------------------------
__global__ __launch_bounds__(256) void gemmo_k(const unsigned short* __restrict__ A,
                                               const unsigned short* __restrict__ Bt,
                                               float* __restrict__ C)
{
    __shared__ unsigned short sA[128 * 64];
    __shared__ unsigned short sB[128 * 64];
    const int t = threadIdx.x;
    const int lane = t & 63, w = t >> 6;
    const int mm = lane & 15, quad = lane >> 4;
    const int wm = w >> 1, wn = w & 1;
    const int m0 = blockIdx.y * 128, n0 = blockIdx.x * 128;

    f32x4 acc[4][4];
#pragma unroll
    for (int i = 0; i < 4; ++i)
#pragma unroll
        for (int j = 0; j < 4; ++j) acc[i][j] = (f32x4){0.f, 0.f, 0.f, 0.f};

    gemm_core(A, Bt, sA, sB, m0, n0, t, acc);

#pragma unroll
    for (int mi = 0; mi < 4; ++mi)
#pragma unroll
        for (int ni = 0; ni < 4; ++ni)
#pragma unroll
            for (int r = 0; r < 4; ++r)
                C[(size_t)(m0 + wm * 64 + mi * 16 + quad * 4 + r) * D_DIM +
                  n0 + wn * 64 + ni * 16 + mm] = acc[mi][ni][r];
}

// ---------------------------------------------------------------------------
// Fused causal flash attention (round-4 verified config: 74.5 us).
// 512 threads (8 waves), 16 q-rows/wave, block covers strips {qt, 15-qt}
// (uniform 34 k-tiles of 64 keys). K/V^T double-buffered, prefetch issued
// right after the per-tile barrier (long compute phase hides the drain).
// l computed via MFMA against all-ones B; sP rows are wave-private.
// ---------------------------------------------------------------------------
__global__ __launch_bounds__(512, 4) void attn_k(const unsigned short* __restrict__ Q,
                                                 const unsigned short* __restrict__ K,
                                                 const unsigned short* __restrict__ Vt,
                                                 unsigned short* __restrict__ ctx)
{
    __shared__ unsigned short sK [2][64 * 64];   // [buf][key][hd]   2x8KB
    __shared__ unsigned short sVT[2][64 * 64];   // [buf][hd][key]   2x8KB
    __shared__ unsigned short sP [128 * 64];     // [qrow][key]      16KB
    const int t = threadIdx.x;
    const int lane = t & 63, w = t >> 6;          // w = 0..7
    const int mm = lane & 15, quad = lane >> 4;
    const int pair = blockIdx.x, bh = blockIdx.y;
    const int b = bh >> 4, hh = bh & 15;
    const size_t rowbase = (size_t)b * S_LEN;
    const int coff = hh * HD;
    const unsigned short* Vh = Vt + (size_t)bh * HD * S_LEN;

    // staging geometry: 512 lanes cover one 64x128B tile per buffer
    const int sc_ = t >> 3, sj = t & 7;
    const int sgk = sj ^ (sc_ & 7);               // XOR chunk swizzle

    u16x8 onesu;
#pragma unroll
    for (int j = 0; j < 8; ++j) onesu[j] = 0x3F80;   // bf16 1.0
    const bf16x8 ones = __builtin_bit_cast(bf16x8, onesu);

    for (int sidx = 0; sidx < 2; ++sidx) {
        const int qt = sidx ? (15 - pair) : pair;
        const int q0 = qt * 128;

        bf16x8 qf[2];
#pragma unroll
        for (int kk = 0; kk < 2; ++kk)
            qf[kk] = *(const bf16x8*)(Q + (rowbase + q0 + w * 16 + mm) * D_DIM
                                        + coff + kk * 32 + quad * 8);
        f32x4 o[4], lacc;
        lacc = (f32x4){0.f, 0.f, 0.f, 0.f};
#pragma unroll
        for (int hf = 0; hf < 4; ++hf) o[hf] = (f32x4){0.f, 0.f, 0.f, 0.f};

        const int nkt = 2 * qt + 2;
        const int qr = q0 + w * 16 + mm;          // this lane's q-row
        const int qrmax = q0 + w * 16 + 15;       // wave's max q-row
        const int m = w * 16 + mm;                // sP row

        // prologue: stage tile 0 into buf 0
        gload16(K  + (rowbase + sc_) * D_DIM + coff + sgk * 8, (void*)&sK[0][t * 8]);
        gload16(Vh + (size_t)sc_ * S_LEN + sgk * 8,            (void*)&sVT[0][t * 8]);

        for (int kt = 0; kt < nkt; ++kt) {
            const int buf = kt & 1;
            __syncthreads();   // buf's loads drained (issued a full phase ago)
            if (kt + 1 < nkt) {
                const int k1 = (kt + 1) * 64;
                gload16(K  + (rowbase + k1 + sc_) * D_DIM + coff + sgk * 8,
                        (void*)&sK[1 - buf][t * 8]);
                gload16(Vh + (size_t)sc_ * S_LEN + k1 + sgk * 8,
                        (void*)&sVT[1 - buf][t * 8]);
            }
            const int k0 = kt * 64;
            if (k0 > qrmax) continue;   // fully masked for this wave

            // S^T = K Q^T : A = K rows, B = Q rows
            f32x4 sacc[4];
#pragma unroll
            for (int kf = 0; kf < 4; ++kf) sacc[kf] = (f32x4){0.f, 0.f, 0.f, 0.f};
#pragma unroll
            for (int kk = 0; kk < 2; ++kk) {
                bf16x8 ak[4];
#pragma unroll
                for (int kf = 0; kf < 4; ++kf) {
                    int key = kf * 16 + mm;
                    int slot = (kk * 4 + quad) ^ (key & 7);
                    ak[kf] = *(const bf16x8*)&sK[buf][key * 64 + slot * 8];
                }
#pragma unroll
                for (int kf = 0; kf < 4; ++kf)
                    sacc[kf] = __builtin_amdgcn_mfma_f32_16x16x32_bf16(ak[kf], qf[kk], sacc[kf], 0, 0, 0);
            }

            // p = exp2(s), causal mask -> 0, pack to wave-private sP rows
            const bool needmask = (k0 + 63) > (q0 + w * 16);
#pragma unroll
            for (int kf = 0; kf < 4; ++kf) {
                float p[4];
#pragma unroll
                for (int r = 0; r < 4; ++r) {
                    p[r] = __builtin_amdgcn_exp2f(sacc[kf][r]);
                    if (needmask && (k0 + kf * 16 + quad * 4 + r) > qr) p[r] = 0.f;
                }
                unsigned lo = pack2(p[0], p[1]), hi = pack2(p[2], p[3]);
                int slot = (kf * 2 + (quad >> 1)) ^ (m & 7);
                *(unsigned long long*)&sP[m * 64 + slot * 8 + (quad & 1) * 4] =
                    ((unsigned long long)hi << 32) | lo;
            }

            // O += P V ; l += P * ones
#pragma unroll
            for (int kk = 0; kk < 2; ++kk) {
                bf16x8 pf, vf[4];
                {
                    int slot = (kk * 4 + quad) ^ (m & 7);
                    pf = *(const bf16x8*)&sP[m * 64 + slot * 8];
                }
#pragma unroll
                for (int hf = 0; hf < 4; ++hf) {
                    int hd = hf * 16 + mm;
                    int slot = (kk * 4 + quad) ^ (hd & 7);
                    vf[hf] = *(const bf16x8*)&sVT[buf][hd * 64 + slot * 8];
                }
                lacc = __builtin_amdgcn_mfma_f32_16x16x32_bf16(pf, ones, lacc, 0, 0, 0);
#pragma unroll
                for (int hf = 0; hf < 4; ++hf)
                    o[hf] = __builtin_amdgcn_mfma_f32_16x16x32_bf16(pf, vf[hf], o[hf], 0, 0, 0);
            }
        }
        __syncthreads();   // all compute done before next strip's prologue restages buf0

        // normalize (l already in C-layout) and store ctx
#pragma unroll
        for (int r = 0; r < 4; ++r) {
            float inv = 1.f / lacc[r];
            int row = q0 + w * 16 + quad * 4 + r;
#pragma unroll
            for (int hf = 0; hf < 4; ++hf)
                ctx[(rowbase + row) * D_DIM + coff + hf * 16 + mm] = f2bf(o[hf][r] * inv);
        }
    }
}

extern "C" void kernel_launch(void* const* d_in, const int* in_sizes, int n_in,
                              void* d_out, int out_size, void* d_ws, size_t ws_size,
                              hipStream_t stream)
{
    const float* x  = (const float*)d_in[0];
    const float* wq = (const float*)d_in[1];
    const float* wk = (const float*)d_in[2];
    const float* wv = (const float*)d_in[3];
    const float* wo = (const float*)d_in[4];

    const size_t XE = (size_t)M_ROWS * D_DIM;   // 8M elems
    const size_t WE = (size_t)D_DIM * D_DIM;    // 1M elems
    unsigned short* ws  = (unsigned short*)d_ws;
    unsigned short* xbf = ws;
    unsigned short* wt0 = xbf + XE;
    unsigned short* wt1 = wt0 + WE;
    unsigned short* wt2 = wt1 + WE;
    unsigned short* wt3 = wt2 + WE;
    unsigned short* qb  = wt3 + WE;
    unsigned short* kb  = qb + XE;
    unsigned short* vt  = kb + XE;      // V stored transposed per head
    unsigned short* cb  = vt + XE;      // ~80 MB total

    prep_k<<<dim3(4096 + 1024), 256, 0, stream>>>(x, wq, wk, wv, wo,
                                                  xbf, wt0, wt1, wt2, wt3);

    gemmqkv_k<<<dim3(3 * D_DIM / 128, M_ROWS / 128), 256, 0, stream>>>(xbf, wt0, qb, kb, vt);

    attn_k<<<dim3(8, BATCH * NH), 512, 0, stream>>>(qb, kb, vt, cb);

    gemmo_k<<<dim3(D_DIM / 128, M_ROWS / 128), 256, 0, stream>>>(cb, wt3, (float*)d_out);
}